// Round 7
// baseline (754.508 us; speedup 1.0000x reference)
//
#include <hip/hip_runtime.h>

typedef unsigned short u16;
typedef unsigned int u32;
typedef __attribute__((ext_vector_type(2))) float f32x2;
typedef __attribute__((ext_vector_type(4))) float f32x4;
typedef __attribute__((ext_vector_type(8))) short s16x8;
typedef __attribute__((ext_vector_type(4))) u16 u16x4;

static constexpr int Hdim = 2048, Idim = 4096, Ndim = 16, Rdim = 128, Lseq = 2048;
static constexpr int NCH = 64, LCH = 32;  // scan chunks, chunk length

__device__ __forceinline__ u16 f2bf(float f) {
  u32 u = __builtin_bit_cast(u32, f);
  u += 0x7fffu + ((u >> 16) & 1u);
  return (u16)(u >> 16);
}
__device__ __forceinline__ float bf2f(u16 u) {
  u32 x = ((u32)u) << 16;
  return __builtin_bit_cast(float, x);
}

// ================= fused prep: x->bf16 + 4 weight transposes =================
__device__ __forceinline__ void tcvt64_body(const float* __restrict__ src, u16* __restrict__ dst,
                                            int C, int ld, int bx, int by, void* smem) {
  u16(*tile)[68] = (u16(*)[68])smem;
  const int c0 = bx * 64, r0 = by * 64;
#pragma unroll
  for (int it = 0; it < 4; ++it) {
    int v = it * 256 + threadIdx.x;
    int row = v >> 4, c4 = v & 15;
    f32x4 d = *(const f32x4*)&src[(size_t)(r0 + row) * C + c0 + c4 * 4];
    u16x4 o = {f2bf(d.x), f2bf(d.y), f2bf(d.z), f2bf(d.w)};
    *(u16x4*)&tile[row][c4 * 4] = o;
  }
  __syncthreads();
#pragma unroll
  for (int it = 0; it < 4; ++it) {
    int v = it * 256 + threadIdx.x;
    int oc = v >> 4, r4 = v & 15;
    u16x4 o = {tile[r4 * 4 + 0][oc], tile[r4 * 4 + 1][oc],
               tile[r4 * 4 + 2][oc], tile[r4 * 4 + 3][oc]};
    *(u16x4*)&dst[(size_t)(c0 + oc) * ld + r0 + r4 * 4] = o;
  }
}

__device__ __forceinline__ void tcvt_body(const float* __restrict__ src, u16* __restrict__ dst,
                                          int R, int C, int dstld, int bx, int by, void* smem) {
  float(*tile)[33] = (float(*)[33])smem;
  int tx = threadIdx.x & 31, ty = threadIdx.x >> 5;
  int c0 = bx * 32, r0 = by * 32;
#pragma unroll
  for (int j = 0; j < 32; j += 8) {
    int r = r0 + ty + j, c = c0 + tx;
    tile[ty + j][tx] = (r < R && c < C) ? src[(size_t)r * C + c] : 0.f;
  }
  __syncthreads();
#pragma unroll
  for (int j = 0; j < 32; j += 8) {
    int c = c0 + ty + j, r = r0 + tx;
    if (c < C && r < R) dst[(size_t)c * dstld + r] = f2bf(tile[tx][ty + j]);
  }
}

static constexpr int PREP_BLOCKS = 2048 + 4096 + 640 + 128 + 2048;

__global__ __launch_bounds__(256)
void k_prep(const float* __restrict__ x, u16* __restrict__ xb,
            const float* __restrict__ W_in, u16* __restrict__ winT,
            const float* __restrict__ W_x, u16* __restrict__ wxt,
            const float* __restrict__ W_dt, u16* __restrict__ wdtT,
            const float* __restrict__ W_out, u16* __restrict__ woutT) {
  __shared__ char smem[64 * 68 * 2];
  int bid = blockIdx.x;
  if (bid < 2048) {  // x [2048][2048] f32 -> bf16 (4M f32 = 1M f32x4)
    int i = bid * 512 + threadIdx.x;
#pragma unroll
    for (int t = 0; t < 2; ++t) {
      f32x4 v = ((const f32x4*)x)[i + t * 256];
      u16x4 o = {f2bf(v.x), f2bf(v.y), f2bf(v.z), f2bf(v.w)};
      ((u16x4*)xb)[i + t * 256] = o;
    }
  } else if (bid < 6144) {  // W_in [2048][8192] -> winT [8192][2048]
    int sub = bid - 2048;
    tcvt64_body(W_in, winT, 2 * Idim, Hdim, sub & 127, sub >> 7, smem);
  } else if (bid < 6784) {  // W_x [4096][160] -> wxt [256(pad)][4096]
    int sub = bid - 6144;
    tcvt_body(W_x, wxt, Idim, 160, Idim, sub % 5, sub / 5, smem);
  } else if (bid < 6912) {  // W_dt [128][4096] -> wdtT [4096][128]
    int sub = bid - 6784;
    tcvt64_body(W_dt, wdtT, Idim, Rdim, sub & 63, sub >> 6, smem);
  } else {  // W_out [4096][2048] -> woutT [2048][4096]
    int sub = bid - 6912;
    tcvt64_body(W_out, woutT, Hdim, Idim, sub & 31, sub >> 5, smem);
  }
}

// ---------- depthwise causal conv (K=4) + bias + silu -> bf16 ----------
__global__ void k_conv(const u16* __restrict__ projb, const float* __restrict__ cw,
                       const float* __restrict__ cb, u16* __restrict__ hcb) {
  int idx = blockIdx.x * 256 + threadIdx.x;  // l*I + i
  int i = idx & (Idim - 1), l = idx >> 12;
  float acc = cb[i];
#pragma unroll
  for (int k = 0; k < 4; ++k) {
    int lk = l - 3 + k;
    if (lk >= 0) acc += cw[i * 4 + k] * bf2f(projb[(size_t)lk * (2 * Idim) + i]);
  }
  float s = acc * (1.f / (1.f + __expf(-acc)));
  hcb[idx] = f2bf(s);
}

// ---------- chunked scan pass 1 ----------
__global__ __launch_bounds__(256)
void k_scan1(const u16* __restrict__ dtfb, const u16* __restrict__ hcb,
             const float* __restrict__ ssm, const float* __restrict__ A_log,
             float* __restrict__ Sloc, float* __restrict__ dtsum) {
  __shared__ float Bs[LCH][16];
  const int c = blockIdx.y;
  const int i = blockIdx.x * 256 + threadIdx.x;
  const int l0 = c * LCH;
  {
    int t = threadIdx.x;
    int l = t >> 3, q = t & 7;
    *(f32x2*)&Bs[l][q * 2] = *(const f32x2*)&ssm[(size_t)(l0 + l) * 256 + 128 + q * 2];
  }
  float a[16];
#pragma unroll
  for (int n4 = 0; n4 < 4; ++n4) {
    f32x4 v = *(const f32x4*)&A_log[(size_t)i * 16 + n4 * 4];
    a[n4 * 4 + 0] = -__expf(v.x);
    a[n4 * 4 + 1] = -__expf(v.y);
    a[n4 * 4 + 2] = -__expf(v.z);
    a[n4 * 4 + 3] = -__expf(v.w);
  }
  __syncthreads();
  float s[16];
#pragma unroll
  for (int n = 0; n < 16; ++n) s[n] = 0.f;
  float dsum = 0.f;
  for (int l = 0; l < LCH; ++l) {
    float dtv = bf2f(dtfb[(size_t)(l0 + l) * Idim + i]);
    float hv = bf2f(hcb[(size_t)(l0 + l) * Idim + i]);
    dsum += dtv;
    float dh = dtv * hv;
#pragma unroll
    for (int n = 0; n < 16; ++n) {
      float dA = __expf(a[n] * dtv);
      s[n] = dA * s[n] + dh * Bs[l][n];
    }
  }
#pragma unroll
  for (int n4 = 0; n4 < 4; ++n4) {
    f32x4 v = {s[n4 * 4], s[n4 * 4 + 1], s[n4 * 4 + 2], s[n4 * 4 + 3]};
    *(f32x4*)&Sloc[((size_t)c * Idim + i) * 16 + n4 * 4] = v;
  }
  dtsum[(size_t)c * Idim + i] = dsum;
}

// ---------- pass 2: inter-chunk prefix ----------
__global__ __launch_bounds__(256)
void k_scan2(const float* __restrict__ Sloc, const float* __restrict__ dtsum,
             const float* __restrict__ A_log, float* __restrict__ sinit) {
  const int idx = blockIdx.x * 256 + threadIdx.x;  // i*16+n
  const float a = -__expf(A_log[idx]);
  const int i = idx >> 4;
  float acc = 0.f;
  for (int c = 0; c < NCH; ++c) {
    size_t o = (size_t)c * (Idim * 16) + idx;
    sinit[o] = acc;
    acc = __expf(a * dtsum[(size_t)c * Idim + i]) * acc + Sloc[o];
  }
}

// ---------- pass 3: seeded local scan + fused epilogue ----------
__global__ __launch_bounds__(256)
void k_scan3(const u16* __restrict__ dtfb, const u16* __restrict__ hcb,
             const float* __restrict__ ssm, const float* __restrict__ A_log,
             const float* __restrict__ Dp, const u16* __restrict__ projb,
             const float* __restrict__ sinit, u16* __restrict__ yb) {
  __shared__ float SBC[LCH][32];
  const int c = blockIdx.y;
  const int i = blockIdx.x * 256 + threadIdx.x;
  const int l0 = c * LCH;
  {
    int t = threadIdx.x;
    int l = t >> 3, q = t & 7;
    *(f32x4*)&SBC[l][q * 4] = *(const f32x4*)&ssm[(size_t)(l0 + l) * 256 + 128 + q * 4];
  }
  float a[16], s[16];
#pragma unroll
  for (int n4 = 0; n4 < 4; ++n4) {
    f32x4 v = *(const f32x4*)&A_log[(size_t)i * 16 + n4 * 4];
    a[n4 * 4 + 0] = -__expf(v.x);
    a[n4 * 4 + 1] = -__expf(v.y);
    a[n4 * 4 + 2] = -__expf(v.z);
    a[n4 * 4 + 3] = -__expf(v.w);
    f32x4 sv = *(const f32x4*)&sinit[((size_t)c * Idim + i) * 16 + n4 * 4];
    s[n4 * 4 + 0] = sv.x;
    s[n4 * 4 + 1] = sv.y;
    s[n4 * 4 + 2] = sv.z;
    s[n4 * 4 + 3] = sv.w;
  }
  const float Di = Dp[i];
  __syncthreads();
  for (int l = 0; l < LCH; ++l) {
    float dtv = bf2f(dtfb[(size_t)(l0 + l) * Idim + i]);
    float hv = bf2f(hcb[(size_t)(l0 + l) * Idim + i]);
    float dh = dtv * hv;
    float y = 0.f;
#pragma unroll
    for (int n = 0; n < 16; ++n) {
      float dA = __expf(a[n] * dtv);
      s[n] = dA * s[n] + dh * SBC[l][n];
      y += s[n] * SBC[l][16 + n];
    }
    float g = bf2f(projb[(size_t)(l0 + l) * (2 * Idim) + Idim + i]);
    y = (y + hv * Di) * (g / (1.f + __expf(-g)));
    yb[(size_t)(l0 + l) * Idim + i] = f2bf(y);
  }
}

// ================= 128-tile MFMA GEMM (m97 structure) =================
__device__ __forceinline__ void gload_lds16(const void* g, void* l) {
  __builtin_amdgcn_global_load_lds((const __attribute__((address_space(1))) void*)g,
                                   (__attribute__((address_space(3))) void*)l, 16, 0, 0);
}

// EPI: 0=f32 store, 5=softplus(v+bias[col]) -> bf16 Caux
template <int EPI>
__device__ __forceinline__ void gemm_body(const u16* __restrict__ A, const u16* __restrict__ Bt,
                                          float* __restrict__ C, u16* __restrict__ Caux,
                                          int N, int K, int kchunk,
                                          const float* __restrict__ bias,
                                          int m0, int n0, int kz) {
  __shared__ u16 As[128 * 32];
  __shared__ u16 Bs[128 * 32];
  const int tid = threadIdx.x;
  const int wave = tid >> 6, lane = tid & 63;
  const int wm = (wave >> 1) * 64, wn = (wave & 1) * 64;
  const int lr = lane >> 2;
  const int lc = lane & 3;
  const int arow = wave * 32;

  f32x4 acc[4][4];
#pragma unroll
  for (int a = 0; a < 4; ++a)
#pragma unroll
    for (int b = 0; b < 4; ++b) acc[a][b] = (f32x4){0.f, 0.f, 0.f, 0.f};

  const int k_begin = kz * kchunk;
  const int k_end = k_begin + kchunk;

  for (int k = k_begin; k < k_end; k += 32) {
#pragma unroll
    for (int j = 0; j < 2; ++j) {
      const u16* ga = A + (size_t)(m0 + arow + j * 16 + lr) * K + k + lc * 8;
      gload_lds16(ga, &As[(arow + j * 16) * 32]);
      const u16* gb = Bt + (size_t)(n0 + arow + j * 16 + lr) * K + k + lc * 8;
      gload_lds16(gb, &Bs[(arow + j * 16) * 32]);
    }
    __syncthreads();
    const int kh = (lane >> 4) * 8;
    const int fr = lane & 15;
    s16x8 af[4], bfr[4];
#pragma unroll
    for (int f = 0; f < 4; ++f) {
      af[f] = *(const s16x8*)&As[(wm + f * 16 + fr) * 32 + kh];
      bfr[f] = *(const s16x8*)&Bs[(wn + f * 16 + fr) * 32 + kh];
    }
#pragma unroll
    for (int fm = 0; fm < 4; ++fm)
#pragma unroll
      for (int fn = 0; fn < 4; ++fn)
        acc[fm][fn] = __builtin_amdgcn_mfma_f32_16x16x32_bf16(af[fm], bfr[fn], acc[fm][fn], 0, 0, 0);
    __syncthreads();
  }

  const int cr = (lane >> 4) * 4, cc = lane & 15;
#pragma unroll
  for (int fm = 0; fm < 4; ++fm)
#pragma unroll
    for (int fn = 0; fn < 4; ++fn)
#pragma unroll
      for (int j = 0; j < 4; ++j) {
        int row = m0 + wm + fm * 16 + cr + j;
        int col = n0 + wn + fn * 16 + cc;
        float v = acc[fm][fn][j];
        if (EPI == 0) {
          C[(size_t)row * N + col] = v;
        } else {
          float xv = v + bias[col];
          Caux[(size_t)row * N + col] = f2bf(fmaxf(xv, 0.f) + log1pf(__expf(-fabsf(xv))));
        }
      }
}

// GEMM3: h @ W_x -> partials [8][2048][256] f32; last-finisher reduces ->
// ssm cols 128..255 (f32) or dt_raw bf16 (cols 0..127)
__global__ __launch_bounds__(256)
void k_gemm3(const u16* __restrict__ A, const u16* __restrict__ Bt, float* __restrict__ Cp,
             float* __restrict__ ssm, u16* __restrict__ dtr, u32* __restrict__ cnt) {
  gemm_body<0>(A, Bt, Cp + (size_t)blockIdx.z * Lseq * 256, nullptr, 256, Idim, Idim / 8,
               nullptr, blockIdx.x * 128, blockIdx.y * 128, blockIdx.z);
  __threadfence();
  __syncthreads();
  __shared__ u32 last;
  if (threadIdx.x == 0) {
    u32 old = atomicAdd(&cnt[blockIdx.y * 16 + blockIdx.x], 1u);
    last = (old == 7u);
  }
  __syncthreads();
  if (!last) return;
  __threadfence();
  const int r0 = blockIdx.x * 128, c0 = blockIdx.y * 128;
#pragma unroll
  for (int j = 0; j < 16; ++j) {
    int pos = j * 256 + threadIdx.x;     // 4096 f32x4 in the 128x128 region
    int r = pos >> 5, cv = pos & 31;
    size_t off = (size_t)(r0 + r) * 256 + c0 + cv * 4;
    f32x4 s = {0.f, 0.f, 0.f, 0.f};
#pragma unroll
    for (int z = 0; z < 8; ++z) {
      f32x4 v = *(const f32x4*)&Cp[(size_t)z * Lseq * 256 + off];
      s.x += v.x; s.y += v.y; s.z += v.z; s.w += v.w;
    }
    if (blockIdx.y == 0) {
      u16x4 o = {f2bf(s.x), f2bf(s.y), f2bf(s.z), f2bf(s.w)};
      *(u16x4*)&dtr[(size_t)(r0 + r) * 128 + cv * 4] = o;
    } else {
      *(f32x4*)&ssm[off] = s;
    }
  }
}

// GEMM4: softplus(dt_raw @ W_dt + b_dt) -> bf16 dtfb [2048][4096]
__global__ __launch_bounds__(256)
void k_gemm4(const u16* __restrict__ A, const u16* __restrict__ Bt, u16* __restrict__ Caux,
             const float* __restrict__ bias) {
  gemm_body<5>(A, Bt, nullptr, Caux, Idim, Rdim, Rdim, bias,
               blockIdx.x * 128, blockIdx.y * 128, 0);
}

// ================= 256x256 8-phase GEMM body (T2+T3+T4+T5) =================
__device__ __forceinline__ void g8_stage(const u16* __restrict__ g, int ld, int row0, int kcol,
                                         u16* lds, int slot, int wid, int lane) {
#pragma unroll
  for (int j = 0; j < 2; ++j) {
    const u16* ga = g + (size_t)(row0 + j * 64 + wid * 8 + (lane >> 3)) * ld
                      + kcol + (((lane & 7) ^ (lane >> 3)) << 3);
    gload_lds16(ga, &lds[slot + j * 4096 + wid * 512]);
  }
}

#define ASLOT(buf, h) (((buf)*2 + (h)) * 8192)
#define BSLOT(buf, h) (32768 + ((buf)*2 + (h)) * 8192)

template <int BUF, int MH, int NH>
__device__ __forceinline__ void g8_compute(const u16* lds, f32x4 (&acc)[2][4][2][2],
                                           int qm, int qn, int lane) {
  const int r16 = lane & 15, kq = lane >> 4;
  s16x8 af[4][2], bq[2][2];
#pragma unroll
  for (int fm = 0; fm < 4; ++fm) {
    int row = qm * 64 + fm * 16 + r16;
#pragma unroll
    for (int ks = 0; ks < 2; ++ks) {
      int ch = (ks * 4 + kq) ^ (row & 7);
      af[fm][ks] = *(const s16x8*)&lds[ASLOT(BUF, MH) + row * 64 + ch * 8];
    }
  }
#pragma unroll
  for (int fn = 0; fn < 2; ++fn) {
    int row = qn * 32 + fn * 16 + r16;
#pragma unroll
    for (int ks = 0; ks < 2; ++ks) {
      int ch = (ks * 4 + kq) ^ (row & 7);
      bq[fn][ks] = *(const s16x8*)&lds[BSLOT(BUF, NH) + row * 64 + ch * 8];
    }
  }
  __builtin_amdgcn_s_setprio(1);
#pragma unroll
  for (int fm = 0; fm < 4; ++fm)
#pragma unroll
    for (int fn = 0; fn < 2; ++fn)
#pragma unroll
      for (int ks = 0; ks < 2; ++ks)
        acc[MH][fm][NH][fn] =
            __builtin_amdgcn_mfma_f32_16x16x32_bf16(af[fm][ks], bq[fn][ks], acc[MH][fm][NH][fn], 0, 0, 0);
  __builtin_amdgcn_s_setprio(0);
}

#define G8BAR()                         \
  do {                                  \
    __builtin_amdgcn_s_barrier();       \
    __builtin_amdgcn_sched_barrier(0);  \
  } while (0)
#define G8VM4() asm volatile("s_waitcnt vmcnt(4)" ::: "memory")

// KLD: global K stride; NITER: K-tiles/2; OUTLD: output ld; EPI: 0=bf16, 1=f32
template <int KLD, int NITER, int OUTLD, int EPI>
__device__ __forceinline__ void g8p_body(const u16* __restrict__ A, const u16* __restrict__ Bt,
                                         float* __restrict__ Cf, u16* __restrict__ Cb,
                                         int m0, int n0, int kbase) {
  extern __shared__ u16 lds[];
  const int tid = threadIdx.x, wid = tid >> 6, lane = tid & 63;
  const int qm = wid >> 2, qn = wid & 3;

  f32x4 acc[2][4][2][2];
#pragma unroll
  for (int a = 0; a < 2; ++a)
#pragma unroll
    for (int b = 0; b < 4; ++b)
#pragma unroll
      for (int c = 0; c < 2; ++c)
#pragma unroll
        for (int d = 0; d < 2; ++d) acc[a][b][c][d] = (f32x4){0.f, 0.f, 0.f, 0.f};

  // prologue
  g8_stage(A, KLD, m0, kbase, lds, ASLOT(0, 0), wid, lane);
  g8_stage(Bt, KLD, n0 + 128, kbase, lds, BSLOT(0, 1), wid, lane);
  g8_stage(A, KLD, m0 + 128, kbase, lds, ASLOT(0, 1), wid, lane);
  g8_stage(Bt, KLD, n0, kbase, lds, BSLOT(0, 0), wid, lane);
  g8_stage(A, KLD, m0, kbase + 64, lds, ASLOT(1, 0), wid, lane);
  g8_stage(Bt, KLD, n0 + 128, kbase + 64, lds, BSLOT(1, 1), wid, lane);

  for (int i = 0; i < NITER - 1; ++i) {
    const int kc0 = kbase + i * 128, kc2 = kc0 + 128, kc3 = kc0 + 192;
    g8_stage(A, KLD, m0 + 128, kc0 + 64, lds, ASLOT(1, 1), wid, lane);
    G8VM4();
    G8BAR();
    g8_compute<0, 0, 0>(lds, acc, qm, qn, lane);
    G8BAR();
    g8_stage(Bt, KLD, n0, kc0 + 64, lds, BSLOT(1, 0), wid, lane);
    G8BAR();
    g8_compute<0, 0, 1>(lds, acc, qm, qn, lane);
    G8BAR();
    g8_stage(A, KLD, m0, kc2, lds, ASLOT(0, 0), wid, lane);
    G8BAR();
    g8_compute<0, 1, 1>(lds, acc, qm, qn, lane);
    G8BAR();
    g8_stage(Bt, KLD, n0 + 128, kc2, lds, BSLOT(0, 1), wid, lane);
    G8BAR();
    g8_compute<0, 1, 0>(lds, acc, qm, qn, lane);
    G8BAR();
    g8_stage(A, KLD, m0 + 128, kc2, lds, ASLOT(0, 1), wid, lane);
    G8VM4();
    G8BAR();
    g8_compute<1, 0, 0>(lds, acc, qm, qn, lane);
    G8BAR();
    g8_stage(Bt, KLD, n0, kc2, lds, BSLOT(0, 0), wid, lane);
    G8BAR();
    g8_compute<1, 0, 1>(lds, acc, qm, qn, lane);
    G8BAR();
    g8_stage(A, KLD, m0, kc3, lds, ASLOT(1, 0), wid, lane);
    G8BAR();
    g8_compute<1, 1, 1>(lds, acc, qm, qn, lane);
    G8BAR();
    g8_stage(Bt, KLD, n0 + 128, kc3, lds, BSLOT(1, 1), wid, lane);
    G8BAR();
    g8_compute<1, 1, 0>(lds, acc, qm, qn, lane);
    G8BAR();
  }

  // peel
  g8_stage(A, KLD, m0 + 128, kbase + (2 * NITER - 1) * 64, lds, ASLOT(1, 1), wid, lane);
  g8_stage(Bt, KLD, n0, kbase + (2 * NITER - 1) * 64, lds, BSLOT(1, 0), wid, lane);
  asm volatile("s_waitcnt vmcnt(0)" ::: "memory");
  G8BAR();
  g8_compute<0, 0, 0>(lds, acc, qm, qn, lane);
  g8_compute<0, 0, 1>(lds, acc, qm, qn, lane);
  g8_compute<0, 1, 1>(lds, acc, qm, qn, lane);
  g8_compute<0, 1, 0>(lds, acc, qm, qn, lane);
  g8_compute<1, 0, 0>(lds, acc, qm, qn, lane);
  g8_compute<1, 0, 1>(lds, acc, qm, qn, lane);
  g8_compute<1, 1, 1>(lds, acc, qm, qn, lane);
  g8_compute<1, 1, 0>(lds, acc, qm, qn, lane);

  const int cr = (lane >> 4) * 4, cc = lane & 15;
#pragma unroll
  for (int mh = 0; mh < 2; ++mh)
#pragma unroll
    for (int fm = 0; fm < 4; ++fm)
#pragma unroll
      for (int nh = 0; nh < 2; ++nh)
#pragma unroll
        for (int fn = 0; fn < 2; ++fn)
#pragma unroll
          for (int j = 0; j < 4; ++j) {
            int row = m0 + mh * 128 + qm * 64 + fm * 16 + cr + j;
            int col = n0 + nh * 128 + qn * 32 + fn * 16 + cc;
            float v = acc[mh][fm][nh][fn][j];
            if (EPI == 0) Cb[(size_t)row * OUTLD + col] = f2bf(v);
            else Cf[(size_t)row * OUTLD + col] = v;
          }
}

// GEMM1: x @ W_in -> bf16 projb [2048][8192]; 256 blocks
__global__ __launch_bounds__(512, 2)
void k_gemm1_8p(const u16* __restrict__ A, const u16* __restrict__ Bt, u16* __restrict__ Cb) {
  const int m0 = (int)(blockIdx.x >> 5) * 256, n0 = (int)(blockIdx.x & 31) * 256;
  g8p_body<2048, 16, 8192, 0>(A, Bt, nullptr, Cb, m0, n0, 0);
}

// GEMM5: y @ W_out -> f32 partials [4][2048][2048]; last-finisher reduces -> out
__global__ __launch_bounds__(512, 2)
void k_gemm5_8p(const u16* __restrict__ A, const u16* __restrict__ Bt, float* __restrict__ Cp,
                float* __restrict__ out, u32* __restrict__ cnt) {
  int bid = blockIdx.x;                  // 64 tiles, XCD-swizzled (64 % 8 == 0)
  int wg = (bid & 7) * 8 + (bid >> 3);
  int m0 = (wg >> 3) * 256, n0 = (wg & 7) * 256;
  float* Cf = Cp + (size_t)blockIdx.y * Lseq * Hdim;
  g8p_body<4096, 8, 2048, 1>(A, Bt, Cf, nullptr, m0, n0, (int)blockIdx.y * 1024);

  __threadfence();
  __syncthreads();
  __shared__ u32 last;
  if (threadIdx.x == 0) {
    u32 old = atomicAdd(&cnt[bid], 1u);
    last = (old == 3u);
  }
  __syncthreads();
  if (!last) return;
  __threadfence();
  const size_t S = (size_t)Lseq * Hdim;
#pragma unroll
  for (int j = 0; j < 32; ++j) {
    int pos = j * 512 + threadIdx.x;     // 16384 f32x4 in the 256x256 tile
    int r = pos >> 6, cv = pos & 63;
    size_t off = (size_t)(m0 + r) * Hdim + n0 + cv * 4;
    f32x4 a = *(const f32x4*)&Cp[off];
    f32x4 b = *(const f32x4*)&Cp[S + off];
    f32x4 c = *(const f32x4*)&Cp[2 * S + off];
    f32x4 d = *(const f32x4*)&Cp[3 * S + off];
    f32x4 r4 = {(a.x + b.x) + (c.x + d.x), (a.y + b.y) + (c.y + d.y),
                (a.z + b.z) + (c.z + d.z), (a.w + b.w) + (c.w + d.w)};
    *(f32x4*)&out[off] = r4;
  }
}

extern "C" void kernel_launch(void* const* d_in, const int* in_sizes, int n_in,
                              void* d_out, int out_size, void* d_ws, size_t ws_size,
                              hipStream_t stream) {
  const float* x = (const float*)d_in[0];
  const float* W_in = (const float*)d_in[1];
  const float* convw = (const float*)d_in[2];
  const float* convb = (const float*)d_in[3];
  const float* W_x = (const float*)d_in[4];
  const float* W_dt = (const float*)d_in[5];
  const float* b_dt = (const float*)d_in[6];
  const float* W_out = (const float*)d_in[7];
  const float* A_log = (const float*)d_in[8];
  const float* Dp = (const float*)d_in[9];
  float* out = (float*)d_out;

  char* w = (char*)d_ws;
  const size_t OFF_PROJ = 0;                                      // projb bf16 32MB; later Cpart5 slices 0-1
  const size_t OFF_HC = OFF_PROJ + (size_t)Lseq * 2 * Idim * 4;   // Cpart3 16MB / Sloc 16MB / Cpart5 slices 2-3
  const size_t OFF_DT = OFF_HC + (size_t)Lseq * Idim * 4;         // dtfb bf16 16MB
  const size_t OFF_XB = OFF_DT + (size_t)Lseq * Idim * 4;         // x bf16 8MB
  const size_t OFF_WIN = OFF_XB + (size_t)Lseq * Hdim * 2;        // W_inT bf16 32MB (dead after GEMM1)
  const size_t OFF_WOUT = OFF_WIN + (size_t)2 * Idim * Hdim * 2;  // W_outT bf16 16MB
  const size_t OFF_HCB = OFF_WOUT + (size_t)Hdim * Idim * 2;      // h bf16 16MB
  const size_t OFF_YB = OFF_HCB + (size_t)Lseq * Idim * 2;        // y bf16 16MB
  const size_t OFF_WX = OFF_YB + (size_t)Lseq * Idim * 2;         // W_xT padded bf16 2MB
  const size_t OFF_WDT = OFF_WX + (size_t)256 * Idim * 2;         // W_dtT bf16 1MB
  const size_t OFF_SSM = OFF_WDT + (size_t)Idim * Rdim * 2;       // ssm f32 2MB
  const size_t OFF_DTR = OFF_SSM + (size_t)Lseq * 256 * 4;        // dt_raw bf16 0.5MB
  const size_t OFF_CNT = OFF_DTR + (size_t)Lseq * 128 * 2;        // counters 1KB

  u16* projb = (u16*)(w + OFF_PROJ);
  u16* dtfb = (u16*)(w + OFF_DT);
  u16* xb = (u16*)(w + OFF_XB);
  u16* winT = (u16*)(w + OFF_WIN);
  u16* woutT = (u16*)(w + OFF_WOUT);
  u16* hcb = (u16*)(w + OFF_HCB);
  u16* yb = (u16*)(w + OFF_YB);
  u16* wxt = (u16*)(w + OFF_WX);
  u16* wdtT = (u16*)(w + OFF_WDT);
  float* ssm = (float*)(w + OFF_SSM);
  u16* dtr = (u16*)(w + OFF_DTR);
  u32* cnt3 = (u32*)(w + OFF_CNT);
  u32* cnt5 = (u32*)(w + OFF_CNT + 256);
  float* Cpart3 = (float*)(w + OFF_HC);                             // 16MB, dead before scan1
  float* Sloc = (float*)(w + OFF_HC);                               // 16MB (after gemm3)
  float* sinit = (float*)(w + OFF_WIN);                             // 16MB (W_inT dead after GEMM1)
  float* dtsum = (float*)(w + OFF_WIN + (size_t)16 * 1024 * 1024);  // 1MB
  float* Cpart5 = (float*)(w + OFF_PROJ);                           // 64MB (projb+Sloc dead after scan3)

  // one memset zeroes wxt pad + counters (and the band between)
  hipMemsetAsync(w + OFF_WX, 0, (OFF_CNT + 1024) - OFF_WX, stream);

  // fused prep: x->bf16 + 4 weight transposes
  k_prep<<<PREP_BLOCKS, 256, 0, stream>>>(x, xb, W_in, winT, W_x, wxt, W_dt, wdtT, W_out, woutT);

  // GEMM1 (8-phase 256^2): projb = bf16(x @ W_in)
  hipFuncSetAttribute((const void*)k_gemm1_8p, hipFuncAttributeMaxDynamicSharedMemorySize, 131072);
  k_gemm1_8p<<<256, 512, 131072, stream>>>(xb, winT, projb);

  // conv + silu -> bf16
  k_conv<<<(size_t)Lseq * Idim / 256, 256, 0, stream>>>(projb, convw, convb, hcb);

  // GEMM3: partials + fused last-block reduce -> ssm f32 (cols 128..255) + dtr bf16
  k_gemm3<<<dim3(Lseq / 128, 2, 8), 256, 0, stream>>>(hcb, wxt, Cpart3, ssm, dtr, cnt3);

  // GEMM4: dtfb = bf16(softplus(dt_raw @ W_dt + b_dt))
  k_gemm4<<<dim3(Lseq / 128, Idim / 128), 256, 0, stream>>>(dtr, wdtT, dtfb, b_dt);

  // chunked scan (3 passes) + fused epilogue -> yb (bf16)
  k_scan1<<<dim3(Idim / 256, NCH), 256, 0, stream>>>(dtfb, hcb, ssm, A_log, Sloc, dtsum);
  k_scan2<<<Idim * 16 / 256, 256, 0, stream>>>(Sloc, dtsum, A_log, sinit);
  k_scan3<<<dim3(Idim / 256, NCH), 256, 0, stream>>>(dtfb, hcb, ssm, A_log, Dp, projb, sinit, yb);

  // GEMM5 (8-phase 256^2, split-K=4) + fused last-block reduce -> out
  hipFuncSetAttribute((const void*)k_gemm5_8p, hipFuncAttributeMaxDynamicSharedMemorySize, 131072);
  k_gemm5_8p<<<dim3(64, 4), 512, 131072, stream>>>(yb, woutT, Cpart5, out, cnt5);
}

// Round 8
// 420.378 us; speedup vs baseline: 1.7948x; 1.7948x over previous
//
#include <hip/hip_runtime.h>

typedef unsigned short u16;
typedef unsigned int u32;
typedef __attribute__((ext_vector_type(2))) float f32x2;
typedef __attribute__((ext_vector_type(4))) float f32x4;
typedef __attribute__((ext_vector_type(8))) short s16x8;
typedef __attribute__((ext_vector_type(4))) u16 u16x4;

static constexpr int Hdim = 2048, Idim = 4096, Ndim = 16, Rdim = 128, Lseq = 2048;
static constexpr int NCH = 64, LCH = 32;  // scan chunks, chunk length

__device__ __forceinline__ u16 f2bf(float f) {
  u32 u = __builtin_bit_cast(u32, f);
  u += 0x7fffu + ((u >> 16) & 1u);
  return (u16)(u >> 16);
}
__device__ __forceinline__ float bf2f(u16 u) {
  u32 x = ((u32)u) << 16;
  return __builtin_bit_cast(float, x);
}

// ================= fused prep: x->bf16 + 4 weight transposes =================
__device__ __forceinline__ void tcvt64_body(const float* __restrict__ src, u16* __restrict__ dst,
                                            int C, int ld, int bx, int by, void* smem) {
  u16(*tile)[68] = (u16(*)[68])smem;
  const int c0 = bx * 64, r0 = by * 64;
#pragma unroll
  for (int it = 0; it < 4; ++it) {
    int v = it * 256 + threadIdx.x;
    int row = v >> 4, c4 = v & 15;
    f32x4 d = *(const f32x4*)&src[(size_t)(r0 + row) * C + c0 + c4 * 4];
    u16x4 o = {f2bf(d.x), f2bf(d.y), f2bf(d.z), f2bf(d.w)};
    *(u16x4*)&tile[row][c4 * 4] = o;
  }
  __syncthreads();
#pragma unroll
  for (int it = 0; it < 4; ++it) {
    int v = it * 256 + threadIdx.x;
    int oc = v >> 4, r4 = v & 15;
    u16x4 o = {tile[r4 * 4 + 0][oc], tile[r4 * 4 + 1][oc],
               tile[r4 * 4 + 2][oc], tile[r4 * 4 + 3][oc]};
    *(u16x4*)&dst[(size_t)(c0 + oc) * ld + r0 + r4 * 4] = o;
  }
}

__device__ __forceinline__ void tcvt_body(const float* __restrict__ src, u16* __restrict__ dst,
                                          int R, int C, int dstld, int bx, int by, void* smem) {
  float(*tile)[33] = (float(*)[33])smem;
  int tx = threadIdx.x & 31, ty = threadIdx.x >> 5;
  int c0 = bx * 32, r0 = by * 32;
#pragma unroll
  for (int j = 0; j < 32; j += 8) {
    int r = r0 + ty + j, c = c0 + tx;
    tile[ty + j][tx] = (r < R && c < C) ? src[(size_t)r * C + c] : 0.f;
  }
  __syncthreads();
#pragma unroll
  for (int j = 0; j < 32; j += 8) {
    int c = c0 + ty + j, r = r0 + tx;
    if (c < C && r < R) dst[(size_t)c * dstld + r] = f2bf(tile[tx][ty + j]);
  }
}

static constexpr int PREP_BLOCKS = 2048 + 4096 + 640 + 128 + 2048;

__global__ __launch_bounds__(256)
void k_prep(const float* __restrict__ x, u16* __restrict__ xb,
            const float* __restrict__ W_in, u16* __restrict__ winT,
            const float* __restrict__ W_x, u16* __restrict__ wxt,
            const float* __restrict__ W_dt, u16* __restrict__ wdtT,
            const float* __restrict__ W_out, u16* __restrict__ woutT) {
  __shared__ char smem[64 * 68 * 2];
  int bid = blockIdx.x;
  if (bid < 2048) {  // x [2048][2048] f32 -> bf16
    int i = bid * 512 + threadIdx.x;
#pragma unroll
    for (int t = 0; t < 2; ++t) {
      f32x4 v = ((const f32x4*)x)[i + t * 256];
      u16x4 o = {f2bf(v.x), f2bf(v.y), f2bf(v.z), f2bf(v.w)};
      ((u16x4*)xb)[i + t * 256] = o;
    }
  } else if (bid < 6144) {  // W_in [2048][8192] -> winT [8192][2048]
    int sub = bid - 2048;
    tcvt64_body(W_in, winT, 2 * Idim, Hdim, sub & 127, sub >> 7, smem);
  } else if (bid < 6784) {  // W_x [4096][160] -> wxt [256(pad)][4096]
    int sub = bid - 6144;
    tcvt_body(W_x, wxt, Idim, 160, Idim, sub % 5, sub / 5, smem);
  } else if (bid < 6912) {  // W_dt [128][4096] -> wdtT [4096][128]
    int sub = bid - 6784;
    tcvt64_body(W_dt, wdtT, Idim, Rdim, sub & 63, sub >> 6, smem);
  } else {  // W_out [4096][2048] -> woutT [2048][4096]
    int sub = bid - 6912;
    tcvt64_body(W_out, woutT, Hdim, Idim, sub & 31, sub >> 5, smem);
  }
}

// ---------- depthwise causal conv (K=4) + bias + silu -> bf16, 4 ch/thread ----------
__global__ __launch_bounds__(256)
void k_conv(const u16* __restrict__ projb, const float* __restrict__ cw,
            const float* __restrict__ cb, u16* __restrict__ hcb) {
  int idx4 = blockIdx.x * 256 + threadIdx.x;  // over L * I/4
  int i = (idx4 & 1023) * 4, l = idx4 >> 10;
  f32x4 acc = *(const f32x4*)&cb[i];
  f32x4 cwv[4];
#pragma unroll
  for (int j = 0; j < 4; ++j) cwv[j] = *(const f32x4*)&cw[(i + j) * 4];
#pragma unroll
  for (int k = 0; k < 4; ++k) {
    int lk = l - 3 + k;
    if (lk >= 0) {
      u16x4 pv = *(const u16x4*)&projb[(size_t)lk * (2 * Idim) + i];
      acc.x += cwv[0][k] * bf2f(pv.x);
      acc.y += cwv[1][k] * bf2f(pv.y);
      acc.z += cwv[2][k] * bf2f(pv.z);
      acc.w += cwv[3][k] * bf2f(pv.w);
    }
  }
  f32x4 s = {acc.x / (1.f + __expf(-acc.x)), acc.y / (1.f + __expf(-acc.y)),
             acc.z / (1.f + __expf(-acc.z)), acc.w / (1.f + __expf(-acc.w))};
  u16x4 o = {f2bf(s.x), f2bf(s.y), f2bf(s.z), f2bf(s.w)};
  *(u16x4*)&hcb[(size_t)l * Idim + i] = o;
}

// ---------- reduce 8 gemm3 partial slices -> ssm f32 + dt_raw bf16 ----------
__global__ __launch_bounds__(256)
void k_red3(const float* __restrict__ Cp, float* __restrict__ ssm, u16* __restrict__ dtr) {
  int i = blockIdx.x * 256 + threadIdx.x;  // over 2048*64 f32x4
  f32x4 s = {0.f, 0.f, 0.f, 0.f};
#pragma unroll
  for (int z = 0; z < 8; ++z) {
    f32x4 v = ((const f32x4*)(Cp + (size_t)z * Lseq * 256))[i];
    s.x += v.x; s.y += v.y; s.z += v.z; s.w += v.w;
  }
  ((f32x4*)ssm)[i] = s;
  int l = i >> 6, c4 = i & 63;
  if (c4 < 32) {
    u16x4 o = {f2bf(s.x), f2bf(s.y), f2bf(s.z), f2bf(s.w)};
    *(u16x4*)&dtr[(size_t)l * 128 + c4 * 4] = o;
  }
}

// ---------- reduce 4 gemm5 partial slices -> out f32 ----------
__global__ __launch_bounds__(256)
void k_red5(const float* __restrict__ Cp, float* __restrict__ out) {
  int i = blockIdx.x * 256 + threadIdx.x;
  const size_t S = (size_t)Lseq * Hdim;
  f32x4 a = ((const f32x4*)Cp)[i];
  f32x4 b = ((const f32x4*)(Cp + S))[i];
  f32x4 c = ((const f32x4*)(Cp + 2 * S))[i];
  f32x4 d = ((const f32x4*)(Cp + 3 * S))[i];
  f32x4 r = {(a.x + b.x) + (c.x + d.x), (a.y + b.y) + (c.y + d.y),
             (a.z + b.z) + (c.z + d.z), (a.w + b.w) + (c.w + d.w)};
  ((f32x4*)out)[i] = r;
}

// ---------- chunked scan pass 1 ----------
__global__ __launch_bounds__(256)
void k_scan1(const u16* __restrict__ dtfb, const u16* __restrict__ hcb,
             const float* __restrict__ ssm, const float* __restrict__ A_log,
             float* __restrict__ Sloc, float* __restrict__ dtsum) {
  __shared__ float Bs[LCH][16];
  const int c = blockIdx.y;
  const int i = blockIdx.x * 256 + threadIdx.x;
  const int l0 = c * LCH;
  {
    int t = threadIdx.x;
    int l = t >> 3, q = t & 7;
    *(f32x2*)&Bs[l][q * 2] = *(const f32x2*)&ssm[(size_t)(l0 + l) * 256 + 128 + q * 2];
  }
  float a[16];
#pragma unroll
  for (int n4 = 0; n4 < 4; ++n4) {
    f32x4 v = *(const f32x4*)&A_log[(size_t)i * 16 + n4 * 4];
    a[n4 * 4 + 0] = -__expf(v.x);
    a[n4 * 4 + 1] = -__expf(v.y);
    a[n4 * 4 + 2] = -__expf(v.z);
    a[n4 * 4 + 3] = -__expf(v.w);
  }
  __syncthreads();
  float s[16];
#pragma unroll
  for (int n = 0; n < 16; ++n) s[n] = 0.f;
  float dsum = 0.f;
  for (int l = 0; l < LCH; ++l) {
    float dtv = bf2f(dtfb[(size_t)(l0 + l) * Idim + i]);
    float hv = bf2f(hcb[(size_t)(l0 + l) * Idim + i]);
    dsum += dtv;
    float dh = dtv * hv;
#pragma unroll
    for (int n = 0; n < 16; ++n) {
      float dA = __expf(a[n] * dtv);
      s[n] = dA * s[n] + dh * Bs[l][n];
    }
  }
#pragma unroll
  for (int n4 = 0; n4 < 4; ++n4) {
    f32x4 v = {s[n4 * 4], s[n4 * 4 + 1], s[n4 * 4 + 2], s[n4 * 4 + 3]};
    *(f32x4*)&Sloc[((size_t)c * Idim + i) * 16 + n4 * 4] = v;
  }
  dtsum[(size_t)c * Idim + i] = dsum;
}

// ---------- pass 2: inter-chunk prefix ----------
__global__ __launch_bounds__(256)
void k_scan2(const float* __restrict__ Sloc, const float* __restrict__ dtsum,
             const float* __restrict__ A_log, float* __restrict__ sinit) {
  const int idx = blockIdx.x * 256 + threadIdx.x;  // i*16+n
  const float a = -__expf(A_log[idx]);
  const int i = idx >> 4;
  float acc = 0.f;
  for (int c = 0; c < NCH; ++c) {
    size_t o = (size_t)c * (Idim * 16) + idx;
    sinit[o] = acc;
    acc = __expf(a * dtsum[(size_t)c * Idim + i]) * acc + Sloc[o];
  }
}

// ---------- pass 3: seeded local scan + fused epilogue ----------
__global__ __launch_bounds__(256)
void k_scan3(const u16* __restrict__ dtfb, const u16* __restrict__ hcb,
             const float* __restrict__ ssm, const float* __restrict__ A_log,
             const float* __restrict__ Dp, const u16* __restrict__ projb,
             const float* __restrict__ sinit, u16* __restrict__ yb) {
  __shared__ float SBC[LCH][32];
  const int c = blockIdx.y;
  const int i = blockIdx.x * 256 + threadIdx.x;
  const int l0 = c * LCH;
  {
    int t = threadIdx.x;
    int l = t >> 3, q = t & 7;
    *(f32x4*)&SBC[l][q * 4] = *(const f32x4*)&ssm[(size_t)(l0 + l) * 256 + 128 + q * 4];
  }
  float a[16], s[16];
#pragma unroll
  for (int n4 = 0; n4 < 4; ++n4) {
    f32x4 v = *(const f32x4*)&A_log[(size_t)i * 16 + n4 * 4];
    a[n4 * 4 + 0] = -__expf(v.x);
    a[n4 * 4 + 1] = -__expf(v.y);
    a[n4 * 4 + 2] = -__expf(v.z);
    a[n4 * 4 + 3] = -__expf(v.w);
    f32x4 sv = *(const f32x4*)&sinit[((size_t)c * Idim + i) * 16 + n4 * 4];
    s[n4 * 4 + 0] = sv.x;
    s[n4 * 4 + 1] = sv.y;
    s[n4 * 4 + 2] = sv.z;
    s[n4 * 4 + 3] = sv.w;
  }
  const float Di = Dp[i];
  __syncthreads();
  for (int l = 0; l < LCH; ++l) {
    float dtv = bf2f(dtfb[(size_t)(l0 + l) * Idim + i]);
    float hv = bf2f(hcb[(size_t)(l0 + l) * Idim + i]);
    float dh = dtv * hv;
    float y = 0.f;
#pragma unroll
    for (int n = 0; n < 16; ++n) {
      float dA = __expf(a[n] * dtv);
      s[n] = dA * s[n] + dh * SBC[l][n];
      y += s[n] * SBC[l][16 + n];
    }
    float g = bf2f(projb[(size_t)(l0 + l) * (2 * Idim) + Idim + i]);
    y = (y + hv * Di) * (g / (1.f + __expf(-g)));
    yb[(size_t)(l0 + l) * Idim + i] = f2bf(y);
  }
}

// ================= 128-tile MFMA GEMM (m97 structure) =================
__device__ __forceinline__ void gload_lds16(const void* g, void* l) {
  __builtin_amdgcn_global_load_lds((const __attribute__((address_space(1))) void*)g,
                                   (__attribute__((address_space(3))) void*)l, 16, 0, 0);
}

// EPI: 0=f32 store, 5=softplus(v+bias[col]) -> bf16 Caux
template <int EPI>
__device__ __forceinline__ void gemm_body(const u16* __restrict__ A, const u16* __restrict__ Bt,
                                          float* __restrict__ C, u16* __restrict__ Caux,
                                          int N, int K, int kchunk,
                                          const float* __restrict__ bias,
                                          int m0, int n0, int kz) {
  __shared__ u16 As[128 * 32];
  __shared__ u16 Bs[128 * 32];
  const int tid = threadIdx.x;
  const int wave = tid >> 6, lane = tid & 63;
  const int wm = (wave >> 1) * 64, wn = (wave & 1) * 64;
  const int lr = lane >> 2;
  const int lc = lane & 3;
  const int arow = wave * 32;

  f32x4 acc[4][4];
#pragma unroll
  for (int a = 0; a < 4; ++a)
#pragma unroll
    for (int b = 0; b < 4; ++b) acc[a][b] = (f32x4){0.f, 0.f, 0.f, 0.f};

  const int k_begin = kz * kchunk;
  const int k_end = k_begin + kchunk;

  for (int k = k_begin; k < k_end; k += 32) {
#pragma unroll
    for (int j = 0; j < 2; ++j) {
      const u16* ga = A + (size_t)(m0 + arow + j * 16 + lr) * K + k + lc * 8;
      gload_lds16(ga, &As[(arow + j * 16) * 32]);
      const u16* gb = Bt + (size_t)(n0 + arow + j * 16 + lr) * K + k + lc * 8;
      gload_lds16(gb, &Bs[(arow + j * 16) * 32]);
    }
    __syncthreads();
    const int kh = (lane >> 4) * 8;
    const int fr = lane & 15;
    s16x8 af[4], bfr[4];
#pragma unroll
    for (int f = 0; f < 4; ++f) {
      af[f] = *(const s16x8*)&As[(wm + f * 16 + fr) * 32 + kh];
      bfr[f] = *(const s16x8*)&Bs[(wn + f * 16 + fr) * 32 + kh];
    }
#pragma unroll
    for (int fm = 0; fm < 4; ++fm)
#pragma unroll
      for (int fn = 0; fn < 4; ++fn)
        acc[fm][fn] = __builtin_amdgcn_mfma_f32_16x16x32_bf16(af[fm], bfr[fn], acc[fm][fn], 0, 0, 0);
    __syncthreads();
  }

  const int cr = (lane >> 4) * 4, cc = lane & 15;
#pragma unroll
  for (int fm = 0; fm < 4; ++fm)
#pragma unroll
    for (int fn = 0; fn < 4; ++fn)
#pragma unroll
      for (int j = 0; j < 4; ++j) {
        int row = m0 + wm + fm * 16 + cr + j;
        int col = n0 + wn + fn * 16 + cc;
        float v = acc[fm][fn][j];
        if (EPI == 0) {
          C[(size_t)row * N + col] = v;
        } else {
          float xv = v + bias[col];
          Caux[(size_t)row * N + col] = f2bf(fmaxf(xv, 0.f) + log1pf(__expf(-fabsf(xv))));
        }
      }
}

// GEMM3: h @ W_x -> partial slices [8][2048][256] f32 (split-K=8, no atomics)
__global__ __launch_bounds__(256)
void k_gemm3(const u16* __restrict__ A, const u16* __restrict__ Bt, float* __restrict__ Cp) {
  gemm_body<0>(A, Bt, Cp + (size_t)blockIdx.z * Lseq * 256, nullptr, 256, Idim, Idim / 8,
               nullptr, blockIdx.x * 128, blockIdx.y * 128, blockIdx.z);
}

// GEMM4: softplus(dt_raw @ W_dt + b_dt) -> bf16 dtfb [2048][4096]
__global__ __launch_bounds__(256)
void k_gemm4(const u16* __restrict__ A, const u16* __restrict__ Bt, u16* __restrict__ Caux,
             const float* __restrict__ bias) {
  gemm_body<5>(A, Bt, nullptr, Caux, Idim, Rdim, Rdim, bias,
               blockIdx.x * 128, blockIdx.y * 128, 0);
}

// ================= 256x256 8-phase GEMM body (T2+T3+T4+T5) =================
__device__ __forceinline__ void g8_stage(const u16* __restrict__ g, int ld, int row0, int kcol,
                                         u16* lds, int slot, int wid, int lane) {
#pragma unroll
  for (int j = 0; j < 2; ++j) {
    const u16* ga = g + (size_t)(row0 + j * 64 + wid * 8 + (lane >> 3)) * ld
                      + kcol + (((lane & 7) ^ (lane >> 3)) << 3);
    gload_lds16(ga, &lds[slot + j * 4096 + wid * 512]);
  }
}

#define ASLOT(buf, h) (((buf)*2 + (h)) * 8192)
#define BSLOT(buf, h) (32768 + ((buf)*2 + (h)) * 8192)

template <int BUF, int MH, int NH>
__device__ __forceinline__ void g8_compute(const u16* lds, f32x4 (&acc)[2][4][2][2],
                                           int qm, int qn, int lane) {
  const int r16 = lane & 15, kq = lane >> 4;
  s16x8 af[4][2], bq[2][2];
#pragma unroll
  for (int fm = 0; fm < 4; ++fm) {
    int row = qm * 64 + fm * 16 + r16;
#pragma unroll
    for (int ks = 0; ks < 2; ++ks) {
      int ch = (ks * 4 + kq) ^ (row & 7);
      af[fm][ks] = *(const s16x8*)&lds[ASLOT(BUF, MH) + row * 64 + ch * 8];
    }
  }
#pragma unroll
  for (int fn = 0; fn < 2; ++fn) {
    int row = qn * 32 + fn * 16 + r16;
#pragma unroll
    for (int ks = 0; ks < 2; ++ks) {
      int ch = (ks * 4 + kq) ^ (row & 7);
      bq[fn][ks] = *(const s16x8*)&lds[BSLOT(BUF, NH) + row * 64 + ch * 8];
    }
  }
  __builtin_amdgcn_s_setprio(1);
#pragma unroll
  for (int fm = 0; fm < 4; ++fm)
#pragma unroll
    for (int fn = 0; fn < 2; ++fn)
#pragma unroll
      for (int ks = 0; ks < 2; ++ks)
        acc[MH][fm][NH][fn] =
            __builtin_amdgcn_mfma_f32_16x16x32_bf16(af[fm][ks], bq[fn][ks], acc[MH][fm][NH][fn], 0, 0, 0);
  __builtin_amdgcn_s_setprio(0);
}

#define G8BAR()                         \
  do {                                  \
    __builtin_amdgcn_s_barrier();       \
    __builtin_amdgcn_sched_barrier(0);  \
  } while (0)
#define G8VM4() asm volatile("s_waitcnt vmcnt(4)" ::: "memory")

// KLD: global K stride; NITER: K-tiles/2; OUTLD: output ld; EPI: 0=bf16, 1=f32
template <int KLD, int NITER, int OUTLD, int EPI>
__device__ __forceinline__ void g8p_body(const u16* __restrict__ A, const u16* __restrict__ Bt,
                                         float* __restrict__ Cf, u16* __restrict__ Cb,
                                         int m0, int n0, int kbase) {
  extern __shared__ u16 lds[];
  const int tid = threadIdx.x, wid = tid >> 6, lane = tid & 63;
  const int qm = wid >> 2, qn = wid & 3;

  f32x4 acc[2][4][2][2];
#pragma unroll
  for (int a = 0; a < 2; ++a)
#pragma unroll
    for (int b = 0; b < 4; ++b)
#pragma unroll
      for (int c = 0; c < 2; ++c)
#pragma unroll
        for (int d = 0; d < 2; ++d) acc[a][b][c][d] = (f32x4){0.f, 0.f, 0.f, 0.f};

  // prologue
  g8_stage(A, KLD, m0, kbase, lds, ASLOT(0, 0), wid, lane);
  g8_stage(Bt, KLD, n0 + 128, kbase, lds, BSLOT(0, 1), wid, lane);
  g8_stage(A, KLD, m0 + 128, kbase, lds, ASLOT(0, 1), wid, lane);
  g8_stage(Bt, KLD, n0, kbase, lds, BSLOT(0, 0), wid, lane);
  g8_stage(A, KLD, m0, kbase + 64, lds, ASLOT(1, 0), wid, lane);
  g8_stage(Bt, KLD, n0 + 128, kbase + 64, lds, BSLOT(1, 1), wid, lane);

  for (int i = 0; i < NITER - 1; ++i) {
    const int kc0 = kbase + i * 128, kc2 = kc0 + 128, kc3 = kc0 + 192;
    g8_stage(A, KLD, m0 + 128, kc0 + 64, lds, ASLOT(1, 1), wid, lane);
    G8VM4();
    G8BAR();
    g8_compute<0, 0, 0>(lds, acc, qm, qn, lane);
    G8BAR();
    g8_stage(Bt, KLD, n0, kc0 + 64, lds, BSLOT(1, 0), wid, lane);
    G8BAR();
    g8_compute<0, 0, 1>(lds, acc, qm, qn, lane);
    G8BAR();
    g8_stage(A, KLD, m0, kc2, lds, ASLOT(0, 0), wid, lane);
    G8BAR();
    g8_compute<0, 1, 1>(lds, acc, qm, qn, lane);
    G8BAR();
    g8_stage(Bt, KLD, n0 + 128, kc2, lds, BSLOT(0, 1), wid, lane);
    G8BAR();
    g8_compute<0, 1, 0>(lds, acc, qm, qn, lane);
    G8BAR();
    g8_stage(A, KLD, m0 + 128, kc2, lds, ASLOT(0, 1), wid, lane);
    G8VM4();
    G8BAR();
    g8_compute<1, 0, 0>(lds, acc, qm, qn, lane);
    G8BAR();
    g8_stage(Bt, KLD, n0, kc2, lds, BSLOT(0, 0), wid, lane);
    G8BAR();
    g8_compute<1, 0, 1>(lds, acc, qm, qn, lane);
    G8BAR();
    g8_stage(A, KLD, m0, kc3, lds, ASLOT(1, 0), wid, lane);
    G8BAR();
    g8_compute<1, 1, 1>(lds, acc, qm, qn, lane);
    G8BAR();
    g8_stage(Bt, KLD, n0 + 128, kc3, lds, BSLOT(1, 1), wid, lane);
    G8BAR();
    g8_compute<1, 1, 0>(lds, acc, qm, qn, lane);
    G8BAR();
  }

  // peel
  g8_stage(A, KLD, m0 + 128, kbase + (2 * NITER - 1) * 64, lds, ASLOT(1, 1), wid, lane);
  g8_stage(Bt, KLD, n0, kbase + (2 * NITER - 1) * 64, lds, BSLOT(1, 0), wid, lane);
  asm volatile("s_waitcnt vmcnt(0)" ::: "memory");
  G8BAR();
  g8_compute<0, 0, 0>(lds, acc, qm, qn, lane);
  g8_compute<0, 0, 1>(lds, acc, qm, qn, lane);
  g8_compute<0, 1, 1>(lds, acc, qm, qn, lane);
  g8_compute<0, 1, 0>(lds, acc, qm, qn, lane);
  g8_compute<1, 0, 0>(lds, acc, qm, qn, lane);
  g8_compute<1, 0, 1>(lds, acc, qm, qn, lane);
  g8_compute<1, 1, 1>(lds, acc, qm, qn, lane);
  g8_compute<1, 1, 0>(lds, acc, qm, qn, lane);

  const int cr = (lane >> 4) * 4, cc = lane & 15;
#pragma unroll
  for (int mh = 0; mh < 2; ++mh)
#pragma unroll
    for (int fm = 0; fm < 4; ++fm)
#pragma unroll
      for (int nh = 0; nh < 2; ++nh)
#pragma unroll
        for (int fn = 0; fn < 2; ++fn)
#pragma unroll
          for (int j = 0; j < 4; ++j) {
            int row = m0 + mh * 128 + qm * 64 + fm * 16 + cr + j;
            int col = n0 + nh * 128 + qn * 32 + fn * 16 + cc;
            float v = acc[mh][fm][nh][fn][j];
            if (EPI == 0) Cb[(size_t)row * OUTLD + col] = f2bf(v);
            else Cf[(size_t)row * OUTLD + col] = v;
          }
}

// GEMM1: x @ W_in -> bf16 projb [2048][8192]; 256 blocks
__global__ __launch_bounds__(512, 2)
void k_gemm1_8p(const u16* __restrict__ A, const u16* __restrict__ Bt, u16* __restrict__ Cb) {
  const int m0 = (int)(blockIdx.x >> 5) * 256, n0 = (int)(blockIdx.x & 31) * 256;
  g8p_body<2048, 16, 8192, 0>(A, Bt, nullptr, Cb, m0, n0, 0);
}

// GEMM5: y @ W_out -> f32 partials [4][2048][2048]; 64 tiles x split-K=4
__global__ __launch_bounds__(512, 2)
void k_gemm5_8p(const u16* __restrict__ A, const u16* __restrict__ Bt, float* __restrict__ Cp) {
  int bid = blockIdx.x;                  // 64 tiles, XCD-swizzled (64 % 8 == 0)
  int wg = (bid & 7) * 8 + (bid >> 3);
  int m0 = (wg >> 3) * 256, n0 = (wg & 7) * 256;
  float* Cf = Cp + (size_t)blockIdx.y * Lseq * Hdim;
  g8p_body<4096, 8, 2048, 1>(A, Bt, Cf, nullptr, m0, n0, (int)blockIdx.y * 1024);
}

extern "C" void kernel_launch(void* const* d_in, const int* in_sizes, int n_in,
                              void* d_out, int out_size, void* d_ws, size_t ws_size,
                              hipStream_t stream) {
  const float* x = (const float*)d_in[0];
  const float* W_in = (const float*)d_in[1];
  const float* convw = (const float*)d_in[2];
  const float* convb = (const float*)d_in[3];
  const float* W_x = (const float*)d_in[4];
  const float* W_dt = (const float*)d_in[5];
  const float* b_dt = (const float*)d_in[6];
  const float* W_out = (const float*)d_in[7];
  const float* A_log = (const float*)d_in[8];
  const float* Dp = (const float*)d_in[9];
  float* out = (float*)d_out;

  char* w = (char*)d_ws;
  const size_t OFF_PROJ = 0;                                      // projb bf16 32MB; later Cpart5 slices 0-1
  const size_t OFF_HC = OFF_PROJ + (size_t)Lseq * 2 * Idim * 4;   // Cpart3 16MB / Sloc 16MB / Cpart5 slices 2-3
  const size_t OFF_DT = OFF_HC + (size_t)Lseq * Idim * 4;         // dtfb bf16 16MB
  const size_t OFF_XB = OFF_DT + (size_t)Lseq * Idim * 4;         // x bf16 8MB
  const size_t OFF_WIN = OFF_XB + (size_t)Lseq * Hdim * 2;        // W_inT bf16 32MB (dead after GEMM1)
  const size_t OFF_WOUT = OFF_WIN + (size_t)2 * Idim * Hdim * 2;  // W_outT bf16 16MB
  const size_t OFF_HCB = OFF_WOUT + (size_t)Hdim * Idim * 2;      // h bf16 16MB
  const size_t OFF_YB = OFF_HCB + (size_t)Lseq * Idim * 2;        // y bf16 16MB
  const size_t OFF_WX = OFF_YB + (size_t)Lseq * Idim * 2;         // W_xT padded bf16 2MB
  const size_t OFF_WDT = OFF_WX + (size_t)256 * Idim * 2;         // W_dtT bf16 1MB
  const size_t OFF_SSM = OFF_WDT + (size_t)Idim * Rdim * 2;       // ssm f32 2MB
  const size_t OFF_DTR = OFF_SSM + (size_t)Lseq * 256 * 4;        // dt_raw bf16 0.5MB

  u16* projb = (u16*)(w + OFF_PROJ);
  u16* dtfb = (u16*)(w + OFF_DT);
  u16* xb = (u16*)(w + OFF_XB);
  u16* winT = (u16*)(w + OFF_WIN);
  u16* woutT = (u16*)(w + OFF_WOUT);
  u16* hcb = (u16*)(w + OFF_HCB);
  u16* yb = (u16*)(w + OFF_YB);
  u16* wxt = (u16*)(w + OFF_WX);
  u16* wdtT = (u16*)(w + OFF_WDT);
  float* ssm = (float*)(w + OFF_SSM);
  u16* dtr = (u16*)(w + OFF_DTR);
  float* Cpart3 = (float*)(w + OFF_HC);                             // 16MB, dead before scan1
  float* Sloc = (float*)(w + OFF_HC);                               // 16MB (after red3)
  float* sinit = (float*)(w + OFF_WIN);                             // 16MB (W_inT dead after GEMM1)
  float* dtsum = (float*)(w + OFF_WIN + (size_t)16 * 1024 * 1024);  // 1MB
  float* Cpart5 = (float*)(w + OFF_PROJ);                           // 64MB (projb+Sloc dead after scan3)

  hipMemsetAsync(wxt, 0, (size_t)256 * Idim * 2, stream);

  // fused prep: x->bf16 + 4 weight transposes
  k_prep<<<PREP_BLOCKS, 256, 0, stream>>>(x, xb, W_in, winT, W_x, wxt, W_dt, wdtT, W_out, woutT);

  // GEMM1 (8-phase 256^2): projb = bf16(x @ W_in)
  hipFuncSetAttribute((const void*)k_gemm1_8p, hipFuncAttributeMaxDynamicSharedMemorySize, 131072);
  k_gemm1_8p<<<256, 512, 131072, stream>>>(xb, winT, projb);

  // conv + silu -> bf16 (4 ch/thread)
  k_conv<<<(size_t)Lseq * Idim / 4 / 256, 256, 0, stream>>>(projb, convw, convb, hcb);

  // GEMM3: partials [8][2048][256], then reduce (+ dt_raw bf16)
  k_gemm3<<<dim3(Lseq / 128, 2, 8), 256, 0, stream>>>(hcb, wxt, Cpart3);
  k_red3<<<Lseq * 64 / 256, 256, 0, stream>>>(Cpart3, ssm, dtr);

  // GEMM4: dtfb = bf16(softplus(dt_raw @ W_dt + b_dt))
  k_gemm4<<<dim3(Lseq / 128, Idim / 128), 256, 0, stream>>>(dtr, wdtT, dtfb, b_dt);

  // chunked scan (3 passes) + fused epilogue -> yb (bf16)
  k_scan1<<<dim3(Idim / 256, NCH), 256, 0, stream>>>(dtfb, hcb, ssm, A_log, Sloc, dtsum);
  k_scan2<<<Idim * 16 / 256, 256, 0, stream>>>(Sloc, dtsum, A_log, sinit);
  k_scan3<<<dim3(Idim / 256, NCH), 256, 0, stream>>>(dtfb, hcb, ssm, A_log, Dp, projb, sinit, yb);

  // GEMM5 (8-phase 256^2, split-K=4): partials then reduce -> out
  hipFuncSetAttribute((const void*)k_gemm5_8p, hipFuncAttributeMaxDynamicSharedMemorySize, 131072);
  k_gemm5_8p<<<dim3(64, 4), 512, 131072, stream>>>(yb, woutT, Cpart5);
  k_red5<<<Lseq * Hdim / 4 / 256, 256, 0, stream>>>(Cpart5, out);
}